// Round 9
// baseline (572.262 us; speedup 1.0000x reference)
//
#include <hip/hip_runtime.h>

// ---- problem constants (fixed by the reference) ----
#define NN      100000          // nodes (== 6250 * 16, == 25000 * 4)
#define IN_DIM  128
#define HID     32
#define ODIM    64
#define L1C     288             // layer1: 8*32 rel cols + 32 root cols
#define L2K     288             // layer2 K: 8*32 S2 cols + 32 h cols
#define NWGS    196             // scatter workgroups
#define NCB     784             // coarse buckets (dst >> 7, 128 nodes each)
#define CCAP    40              // per-(wg,cb) capacity (mean 10.4)
#define RECCAP  2304            // per-cb record LDS buffer (mean 2041, +5.8 sigma)
#define G2ST    296             // LDS tile row stride (288 + 8 pad)

using bf16x8 = __attribute__((ext_vector_type(8))) short;
using f32x4  = __attribute__((ext_vector_type(4))) float;

__device__ __forceinline__ float bf2f(short s) {
    unsigned int u = ((unsigned int)(unsigned short)s) << 16;
    float f; __builtin_memcpy(&f, &u, 4); return f;
}
__device__ __forceinline__ short f2bf(float f) {
    unsigned int u; __builtin_memcpy(&u, &f, 4);
    u += 0x7fffu + ((u >> 16) & 1u);   // RNE
    return (short)(u >> 16);
}
__device__ __forceinline__ float ldf(const void* p, int i, int f32) {
    return f32 ? ((const float*)p)[i] : bf2f(((const short*)p)[i]);
}
__device__ __forceinline__ int ldi(const int* p, long long i, int i64) {
    return i64 ? p[2 * i] : p[(int)i];
}

// ---- per-input dtype detection ----
__global__ __launch_bounds__(256) void detect(const short* __restrict__ x,
                                              const short* __restrict__ W1,
                                              const short* __restrict__ r1,
                                              const short* __restrict__ W2,
                                              const short* __restrict__ r2,
                                              const short* __restrict__ lw,
                                              const int* __restrict__ ei,
                                              const int* __restrict__ et,
                                              int* __restrict__ flags) {
    __shared__ int cnt[8];
    if (threadIdx.x < 8) cnt[threadIdx.x] = 0;
    __syncthreads();
    const short* ptrs[6] = {x, W1, r1, W2, r2, lw};
    const int    nsmp[6] = {2048, 2048, 2048, 2048, 1024, 64};
    for (int j = 0; j < 6; ++j) {
        int w = 0;
        for (int i = threadIdx.x; i < nsmp[j]; i += 256) {
            unsigned int s = (unsigned short)ptrs[j][2 * i];
            unsigned int e = (s >> 7) & 0xFF;
            if (e >= 140u || (e >= 1u && e <= 100u)) w++;
        }
        if (w) atomicAdd(&cnt[j], w);
    }
    int wi = 0, wt = 0;
    if (threadIdx.x < 128) {
        if (ei[2 * threadIdx.x + 1] != 0) wi = 1;
        if (et[2 * threadIdx.x + 1] != 0) wt = 1;
    }
    if (wi) atomicAdd(&cnt[6], 1);
    if (wt) atomicAdd(&cnt[7], 1);
    __syncthreads();
    if (threadIdx.x == 0) {
        const int ns[6] = {2048, 2048, 2048, 2048, 1024, 64};
        for (int j = 0; j < 6; ++j) flags[j] = (cnt[j] * 4 > ns[j]) ? 1 : 0;
        flags[6] = (cnt[6] == 0) ? 1 : 0;
        flags[7] = (cnt[7] == 0) ? 1 : 0;
    }
}

// ---- weight prep ----
__global__ __launch_bounds__(256) void prep_w1(const void* __restrict__ W1,
                                               const void* __restrict__ root1,
                                               short* __restrict__ w1t,
                                               const int* __restrict__ flags) {
    int i = blockIdx.x * 256 + threadIdx.x;
    if (i >= L1C * IN_DIM) return;
    int c = i >> 7, f = i & 127;
    float v;
    if (c < 256) { int r = c >> 5, h = c & 31; v = ldf(W1, (r * IN_DIM + f) * HID + h, flags[1]); }
    else         { v = ldf(root1, f * HID + (c - 256), flags[2]); }
    w1t[c * IN_DIM + f] = f2bf(v);
}
__global__ __launch_bounds__(256) void prep_w2c(const void* __restrict__ W2,
                                                const void* __restrict__ root2,
                                                short* __restrict__ w2ct,
                                                const int* __restrict__ flags) {
    int i = blockIdx.x * 256 + threadIdx.x;
    if (i >= ODIM * L2K) return;
    int c = i / L2K, k = i % L2K;
    float v;
    if (k < 256) { int r = k >> 5, kk = k & 31; v = ldf(W2, (r * HID + kk) * ODIM + c, flags[3]); }
    else         { v = ldf(root2, (k - 256) * ODIM + c, flags[4]); }
    w2ct[c * L2K + k] = f2bf(v);
}
__global__ __launch_bounds__(256) void prep_small(const short* __restrict__ b1,
                                                  const short* __restrict__ b2,
                                                  const void* __restrict__ lin_w,
                                                  const short* __restrict__ lin_b,
                                                  short* __restrict__ smallc,
                                                  const int* __restrict__ flags) {
    int i = threadIdx.x;
    if (i < 32)        smallc[i] = b1[i];
    else if (i < 96)   smallc[i] = b2[i - 32];
    else if (i < 224)  smallc[i] = f2bf(ldf(lin_w, i - 96, flags[5]));
    else if (i < 226)  smallc[i] = lin_b[i - 224];
}

// ---- CSR pass 1: WG-private coarse-bucket scatter ----
// record = (dst&127)<<20 | src<<3 | rel
__global__ __launch_bounds__(1024) void scatter_coarse(const int* __restrict__ ei,
                                                       const int* __restrict__ et,
                                                       int* __restrict__ cnt,
                                                       int* __restrict__ seg, int E,
                                                       const int* __restrict__ flags) {
    __shared__ int cur[NCB];
    if (threadIdx.x < NCB) cur[threadIdx.x] = 0;
    __syncthreads();
    int i64 = flags[6], t64 = flags[7];
    int epw = (E + NWGS - 1) / NWGS;
    int lo = blockIdx.x * epw;
    int hi = lo + epw; if (hi > E) hi = E;
    for (int i = lo + threadIdx.x; i < hi; i += 1024) {
        int s = ldi(ei, i, i64);
        int d = ldi(ei, (long long)E + i, i64);
        int r = ldi(et, i, t64);
        int cb = d >> 7;
        int pos = atomicAdd(&cur[cb], 1);
        if (pos < CCAP)
            seg[(cb * NWGS + (int)blockIdx.x) * CCAP + pos] = ((d & 127) << 20) | (s << 3) | r;
    }
    __syncthreads();
    if (threadIdx.x < NCB) {
        int c = cur[threadIdx.x];
        cnt[blockIdx.x * NCB + threadIdx.x] = c < CCAP ? c : CCAP;
    }
}

// ---- CSR pass 2: scan per-cb totals -> cbBase; off[NN] = E ----
__global__ __launch_bounds__(1024) void cb_scan(const int* __restrict__ cnt,
                                                int* __restrict__ cbBase,
                                                int* __restrict__ off) {
    __shared__ int s[1024];
    int t = threadIdx.x;
    int tot = 0;
    if (t < NCB)
        for (int g = 0; g < NWGS; ++g) tot += cnt[g * NCB + t];
    s[t] = tot; __syncthreads();
    for (int o = 1; o < 1024; o <<= 1) {
        int v = (t >= o) ? s[t - o] : 0;
        __syncthreads();
        s[t] += v;
        __syncthreads();
    }
    if (t < NCB) cbBase[t] = s[t] - tot;
    if (t == NCB - 1) off[NN] = s[t];
}

// ---- CSR pass 3: per-cb (128 nodes) LDS sort -> off/inv_deg + packed ----
__global__ __launch_bounds__(256) void build_cb(const int* __restrict__ cnt,
                                                const int* __restrict__ seg,
                                                const int* __restrict__ cbBase,
                                                int* __restrict__ off,
                                                float* __restrict__ inv_deg,
                                                int* __restrict__ packed) {
    __shared__ int cntl[NWGS], soff[NWGS];
    __shared__ int recs[RECCAP];
    __shared__ int degl[128], basel[128], kcur[128];
    __shared__ int stmp[256];
    int cb = blockIdx.x, tid = threadIdx.x;
    if (tid < NWGS) cntl[tid] = cnt[tid * NCB + cb];
    if (tid < 128) degl[tid] = 0;
    __syncthreads();
    int v = (tid < NWGS) ? cntl[tid] : 0;
    stmp[tid] = v; __syncthreads();
    for (int o = 1; o < 256; o <<= 1) {
        int u = (tid >= o) ? stmp[tid - o] : 0;
        __syncthreads();
        stmp[tid] += u;
        __syncthreads();
    }
    if (tid < NWGS) soff[tid] = stmp[tid] - v;
    int tot = stmp[255]; if (tot > RECCAP) tot = RECCAP;
    __syncthreads();
    int wave = tid >> 6, lane = tid & 63;
    for (int g = wave; g < NWGS; g += 4) {
        int c = cntl[g], b = soff[g];
        const int* sp = seg + (cb * NWGS + g) * CCAP;
        for (int e = lane; e < c; e += 64)
            if (b + e < RECCAP) recs[b + e] = sp[e];
    }
    __syncthreads();
    for (int i = tid; i < tot; i += 256) atomicAdd(&degl[recs[i] >> 20], 1);
    __syncthreads();
    int dv = (tid < 128) ? degl[tid] : 0;
    stmp[tid] = dv; __syncthreads();
    for (int o = 1; o < 128; o <<= 1) {
        int u = (tid >= o) ? stmp[tid - o] : 0;
        __syncthreads();
        stmp[tid] += u;
        __syncthreads();
    }
    int gbase = cbBase[cb];
    if (tid < 128) {
        int excl = stmp[tid] - dv;
        basel[tid] = excl;
        kcur[tid] = 0;
        int node = cb * 128 + tid;
        if (node < NN) {
            off[node] = gbase + excl;
            inv_deg[node] = 1.0f / (float)(dv > 1 ? dv : 1);
        }
    }
    __syncthreads();
    for (int i = tid; i < tot; i += 256) {
        int rec = recs[i];
        int n = rec >> 20;
        int p = atomicAdd(&kcur[n], 1);
        packed[gbase + basel[n] + p] = rec & 0xFFFFF;   // src<<3 | rel
    }
}

// ---- GEMM1: [N,128] x w1t[288,128]^T -> xw [N,288] bf16; 64 rows/wave
__global__ __launch_bounds__(256) void gemm1(const void* __restrict__ x,
                                             const short* __restrict__ w1t,
                                             short* __restrict__ xw,
                                             const int* __restrict__ flags) {
    int wave = threadIdx.x >> 6, lane = threadIdx.x & 63;
    int m = lane & 15, quad = lane >> 4;
    int row0 = (blockIdx.x * 4 + wave) * 64;
    if (row0 >= NN) return;

    bf16x8 a[4][4];
    int fp32 = flags[0];
#pragma unroll
    for (int t = 0; t < 4; ++t) {
        int row = row0 + t * 16 + m;
        int rc = row < NN ? row : NN - 1;
        if (fp32) {
            const float* xr = (const float*)x + rc * IN_DIM + quad * 8;
#pragma unroll
            for (int kt = 0; kt < 4; ++kt) {
                const f32x4* q = (const f32x4*)(xr + kt * 32);
                f32x4 u0 = q[0], u1 = q[1];
                bf16x8 tt;
                tt[0] = f2bf(u0[0]); tt[1] = f2bf(u0[1]); tt[2] = f2bf(u0[2]); tt[3] = f2bf(u0[3]);
                tt[4] = f2bf(u1[0]); tt[5] = f2bf(u1[1]); tt[6] = f2bf(u1[2]); tt[7] = f2bf(u1[3]);
                a[t][kt] = tt;
            }
        } else {
            const short* xr = (const short*)x + rc * IN_DIM + quad * 8;
#pragma unroll
            for (int kt = 0; kt < 4; ++kt) a[t][kt] = *(const bf16x8*)(xr + kt * 32);
        }
    }

    for (int ct = 0; ct < 18; ++ct) {
        const short* wp = w1t + (ct * 16 + m) * IN_DIM + quad * 8;
        bf16x8 b[4];
#pragma unroll
        for (int kt = 0; kt < 4; ++kt) b[kt] = *(const bf16x8*)(wp + kt * 32);
#pragma unroll
        for (int t = 0; t < 4; ++t) {
            f32x4 acc = {0.f, 0.f, 0.f, 0.f};
#pragma unroll
            for (int kt = 0; kt < 4; ++kt)
                acc = __builtin_amdgcn_mfma_f32_16x16x32_bf16(a[t][kt], b[kt], acc, 0, 0, 0);
#pragma unroll
            for (int i = 0; i < 4; ++i) {
                int r = row0 + t * 16 + quad * 4 + i;
                if (r < NN) xw[r * L1C + ct * 16 + m] = f2bf(acc[i]);
            }
        }
    }
}

// ---- layer-1 aggregation: one 64-lane wave per node, halves interleave edges
// (8 independent gathers in flight per wave) -> h [N,32] bf16 (ReLU'd)
__global__ __launch_bounds__(256) void agg1(const short* __restrict__ xw,
                                            const int* __restrict__ off,
                                            const int* __restrict__ packed,
                                            const float* __restrict__ inv_deg,
                                            const short* __restrict__ smallc,
                                            short* __restrict__ h) {
    int tid = threadIdx.x;
    int wave = tid >> 6, lane = tid & 63;
    int half = lane >> 5, l31 = lane & 31;
    int node = blockIdx.x * 4 + wave;            // NN % 4 == 0
    int s = off[node], e = off[node + 1];
    float acc = 0.f;
    int i = s + half;                            // this half owns every other edge
    for (; i + 6 < e; i += 8) {
        int pk0 = packed[i], pk1 = packed[i + 2], pk2 = packed[i + 4], pk3 = packed[i + 6];
        float v0 = bf2f(xw[(pk0 >> 3) * L1C + (pk0 & 7) * 32 + l31]);
        float v1 = bf2f(xw[(pk1 >> 3) * L1C + (pk1 & 7) * 32 + l31]);
        float v2 = bf2f(xw[(pk2 >> 3) * L1C + (pk2 & 7) * 32 + l31]);
        float v3 = bf2f(xw[(pk3 >> 3) * L1C + (pk3 & 7) * 32 + l31]);
        acc += (v0 + v1) + (v2 + v3);
    }
    for (; i < e; i += 2) {
        int pk = packed[i];
        acc += bf2f(xw[(pk >> 3) * L1C + (pk & 7) * 32 + l31]);
    }
    acc += __shfl_down(acc, 32, 64);             // combine halves
    if (half == 0) {
        float v = acc * inv_deg[node] + bf2f(xw[node * L1C + 256 + l31]) + bf2f(smallc[l31]);
        h[node * HID + l31] = f2bf(v > 0.f ? v : 0.f);
    }
}

// ---- fused layer-2: LDS-atomic aggregate -> bf16 tile -> MFMA -> classify
__global__ __launch_bounds__(256) void agg2_fused(const short* __restrict__ h,
                                                  const int* __restrict__ off,
                                                  const int* __restrict__ packed,
                                                  const float* __restrict__ inv_deg,
                                                  const short* __restrict__ w2ct,
                                                  const short* __restrict__ smallc,
                                                  float* __restrict__ out) {
    __shared__ float g2f[16][256];                    // 16 KB fp32 accumulators
    __shared__ __align__(16) short g2l[16 * G2ST];    // 9.25 KB bf16 tile
    __shared__ float red[4][16][2];
    int tid = threadIdx.x;
    int l31 = tid & 31, gi = tid >> 5;
    int row0 = blockIdx.x * 16;                       // NN % 16 == 0

    // zero accumulators
#pragma unroll
    for (int j = 0; j < 16; ++j) g2f[tid >> 4][(tid & 15) * 16 + j] = 0.f;
    __syncthreads();

    // phase A: each 32-lane group streams 2 nodes' edges; ds_add_f32 accumulate
    // (no register dependency chain -> 4 loads in flight per group)
    for (int s2 = 0; s2 < 2; ++s2) {
        int ln = gi * 2 + s2;
        int n = row0 + ln;
        int st = off[n], e = off[n + 1];
        float* rowp = &g2f[ln][0];
        int i = st;
        for (; i + 3 < e; i += 4) {
            int pk0 = packed[i], pk1 = packed[i + 1], pk2 = packed[i + 2], pk3 = packed[i + 3];
            float v0 = bf2f(h[(pk0 >> 3) * HID + l31]);
            float v1 = bf2f(h[(pk1 >> 3) * HID + l31]);
            float v2 = bf2f(h[(pk2 >> 3) * HID + l31]);
            float v3 = bf2f(h[(pk3 >> 3) * HID + l31]);
            atomicAdd(rowp + (pk0 & 7) * 32 + l31, v0);
            atomicAdd(rowp + (pk1 & 7) * 32 + l31, v1);
            atomicAdd(rowp + (pk2 & 7) * 32 + l31, v2);
            atomicAdd(rowp + (pk3 & 7) * 32 + l31, v3);
        }
        for (; i < e; ++i) {
            int pk = packed[i];
            atomicAdd(rowp + (pk & 7) * 32 + l31, bf2f(h[(pk >> 3) * HID + l31]));
        }
    }
    __syncthreads();

    // scale + convert to bf16 tile, append root h
    {
        int row = tid >> 4, cb = (tid & 15) * 16;
        float sc = inv_deg[row0 + row];
#pragma unroll
        for (int j = 0; j < 16; ++j)
            g2l[row * G2ST + cb + j] = f2bf(g2f[row][cb + j] * sc);
        int c2 = (tid & 15) * 2;
        g2l[row * G2ST + 256 + c2]     = h[(row0 + row) * HID + c2];
        g2l[row * G2ST + 256 + c2 + 1] = h[(row0 + row) * HID + c2 + 1];
    }
    __syncthreads();

    // phase B: 4 waves, wave = 16-col block; MFMA over K=288 from LDS
    int wave = tid >> 6, lane = tid & 63;
    int m = lane & 15, quad = lane >> 4;
    const short* wp = w2ct + (wave * 16 + m) * L2K + quad * 8;
    bf16x8 a[9], b[9];
#pragma unroll
    for (int kt = 0; kt < 9; ++kt) {
        b[kt] = *(const bf16x8*)(wp + kt * 32);
        a[kt] = *(const bf16x8*)(&g2l[m * G2ST + quad * 8 + kt * 32]);
    }
    f32x4 acc = {0.f, 0.f, 0.f, 0.f};
#pragma unroll
    for (int kt = 0; kt < 9; ++kt)
        acc = __builtin_amdgcn_mfma_f32_16x16x32_bf16(a[kt], b[kt], acc, 0, 0, 0);

    int c = wave * 16 + m;
    float lw0 = bf2f(smallc[96 + c * 2 + 0]);
    float lw1 = bf2f(smallc[96 + c * 2 + 1]);
    float b2c = bf2f(smallc[32 + c]);
    float pr0[4], pr1[4];
#pragma unroll
    for (int i = 0; i < 4; ++i) {
        float v = acc[i] + b2c;
        pr0[i] = v * lw0;
        pr1[i] = v * lw1;
    }
#pragma unroll
    for (int o = 1; o < 16; o <<= 1) {
#pragma unroll
        for (int i = 0; i < 4; ++i) {
            pr0[i] += __shfl_xor(pr0[i], o, 64);
            pr1[i] += __shfl_xor(pr1[i], o, 64);
        }
    }
    if (m == 0) {
#pragma unroll
        for (int i = 0; i < 4; ++i) {
            red[wave][quad * 4 + i][0] = pr0[i];
            red[wave][quad * 4 + i][1] = pr1[i];
        }
    }
    __syncthreads();
    if (tid < 32) {
        int row = tid >> 1, j = tid & 1;
        float v = red[0][row][j] + red[1][row][j] + red[2][row][j] + red[3][row][j]
                + bf2f(smallc[224 + j]);
        out[(row0 + row) * 2 + j] = v;
    }
}

extern "C" void kernel_launch(void* const* d_in, const int* in_sizes, int n_in,
                              void* d_out, int out_size, void* d_ws, size_t ws_size,
                              hipStream_t stream) {
    const void* x     = d_in[0];
    const int*  ei    = (const int*)d_in[1];
    const int*  etype = (const int*)d_in[2];
    const void* W1    = d_in[3];
    const void* root1 = d_in[4];
    const void* b1    = d_in[5];
    const void* W2    = d_in[6];
    const void* root2 = d_in[7];
    const void* b2    = d_in[8];
    const void* lin_w = d_in[9];
    const void* lin_b = d_in[10];
    float* out = (float*)d_out;          // fp32 output (verified round 4)

    const int E = in_sizes[2];          // 1,600,000

    // workspace carve (256B aligned). Peak ~97 MB.
    char* p = (char*)d_ws;
    auto alloc = [&](size_t bytes) { char* r = p; p += (bytes + 255) & ~(size_t)255; return (void*)r; };
    int*   flags   = (int*)  alloc(256);
    int*   off     = (int*)  alloc((size_t)(NN + 1) * 4);
    float* inv_deg = (float*)alloc((size_t)NN * 4);
    int*   packed  = (int*)  alloc((size_t)E * 4);
    int*   cnt     = (int*)  alloc((size_t)NWGS * NCB * 4);
    int*   cbBase  = (int*)  alloc((size_t)NCB * 4);
    int*   seg     = (int*)  alloc((size_t)NCB * NWGS * CCAP * 4);   // 24.6 MB
    short* w1t     = (short*)alloc((size_t)L1C * IN_DIM * 2);
    short* w2ct    = (short*)alloc((size_t)ODIM * L2K * 2);
    short* smallc  = (short*)alloc(256 * 2);
    short* h       = (short*)alloc((size_t)NN * HID * 2);
    short* xw1     = (short*)alloc((size_t)NN * L1C * 2);            // 57.6 MB

    detect<<<1, 256, 0, stream>>>((const short*)x, (const short*)W1, (const short*)root1,
                                  (const short*)W2, (const short*)root2, (const short*)lin_w,
                                  ei, etype, flags);
    prep_w1<<<(L1C * IN_DIM + 255) / 256, 256, 0, stream>>>(W1, root1, w1t, flags);
    prep_w2c<<<(ODIM * L2K + 255) / 256, 256, 0, stream>>>(W2, root2, w2ct, flags);
    prep_small<<<1, 256, 0, stream>>>((const short*)b1, (const short*)b2, lin_w,
                                      (const short*)lin_b, smallc, flags);

    scatter_coarse<<<NWGS, 1024, 0, stream>>>(ei, etype, cnt, seg, E, flags);
    cb_scan<<<1, 1024, 0, stream>>>(cnt, cbBase, off);
    build_cb<<<NCB, 256, 0, stream>>>(cnt, seg, cbBase, off, inv_deg, packed);

    gemm1<<<((NN + 63) / 64 + 3) / 4, 256, 0, stream>>>(x, w1t, xw1, flags);
    agg1<<<NN / 4, 256, 0, stream>>>(xw1, off, packed, inv_deg, smallc, h);
    agg2_fused<<<NN / 16, 256, 0, stream>>>(h, off, packed, inv_deg, w2ct, smallc, out);
}

// Round 10
// 327.973 us; speedup vs baseline: 1.7448x; 1.7448x over previous
//
#include <hip/hip_runtime.h>

// ---- problem constants (fixed by the reference) ----
#define NN      100000          // nodes (== 6250 * 16)
#define IN_DIM  128
#define HID     32
#define ODIM    64
#define L1C     288             // layer1: 8*32 rel cols + 32 root cols
#define L2K     288             // layer2 K: 8*32 S2 cols + 32 h cols
#define NWGS    196             // scatter workgroups
#define NCB     784             // coarse buckets (dst >> 7, 128 nodes each)
#define CCAP    40              // per-(wg,cb) capacity (mean 10.4)
#define RECCAP  2304            // per-cb record LDS buffer (mean 2041, +5.8 sigma)
#define G2ST    296             // LDS tile row stride (288 + 8 pad)

using bf16x8 = __attribute__((ext_vector_type(8))) short;
using f32x4  = __attribute__((ext_vector_type(4))) float;

__device__ __forceinline__ float bf2f(short s) {
    unsigned int u = ((unsigned int)(unsigned short)s) << 16;
    float f; __builtin_memcpy(&f, &u, 4); return f;
}
__device__ __forceinline__ short f2bf(float f) {
    unsigned int u; __builtin_memcpy(&u, &f, 4);
    u += 0x7fffu + ((u >> 16) & 1u);   // RNE
    return (short)(u >> 16);
}
__device__ __forceinline__ float ldf(const void* p, int i, int f32) {
    return f32 ? ((const float*)p)[i] : bf2f(((const short*)p)[i]);
}
__device__ __forceinline__ int ldi(const int* p, long long i, int i64) {
    return i64 ? p[2 * i] : p[(int)i];
}

// ---- per-input dtype detection ----
__global__ __launch_bounds__(256) void detect(const short* __restrict__ x,
                                              const short* __restrict__ W1,
                                              const short* __restrict__ r1,
                                              const short* __restrict__ W2,
                                              const short* __restrict__ r2,
                                              const short* __restrict__ lw,
                                              const int* __restrict__ ei,
                                              const int* __restrict__ et,
                                              int* __restrict__ flags) {
    __shared__ int cnt[8];
    if (threadIdx.x < 8) cnt[threadIdx.x] = 0;
    __syncthreads();
    const short* ptrs[6] = {x, W1, r1, W2, r2, lw};
    const int    nsmp[6] = {2048, 2048, 2048, 2048, 1024, 64};
    for (int j = 0; j < 6; ++j) {
        int w = 0;
        for (int i = threadIdx.x; i < nsmp[j]; i += 256) {
            unsigned int s = (unsigned short)ptrs[j][2 * i];
            unsigned int e = (s >> 7) & 0xFF;
            if (e >= 140u || (e >= 1u && e <= 100u)) w++;
        }
        if (w) atomicAdd(&cnt[j], w);
    }
    int wi = 0, wt = 0;
    if (threadIdx.x < 128) {
        if (ei[2 * threadIdx.x + 1] != 0) wi = 1;
        if (et[2 * threadIdx.x + 1] != 0) wt = 1;
    }
    if (wi) atomicAdd(&cnt[6], 1);
    if (wt) atomicAdd(&cnt[7], 1);
    __syncthreads();
    if (threadIdx.x == 0) {
        const int ns[6] = {2048, 2048, 2048, 2048, 1024, 64};
        for (int j = 0; j < 6; ++j) flags[j] = (cnt[j] * 4 > ns[j]) ? 1 : 0;
        flags[6] = (cnt[6] == 0) ? 1 : 0;
        flags[7] = (cnt[7] == 0) ? 1 : 0;
    }
}

// ---- weight prep ----
__global__ __launch_bounds__(256) void prep_w1(const void* __restrict__ W1,
                                               const void* __restrict__ root1,
                                               short* __restrict__ w1t,
                                               const int* __restrict__ flags) {
    int i = blockIdx.x * 256 + threadIdx.x;
    if (i >= L1C * IN_DIM) return;
    int c = i >> 7, f = i & 127;
    float v;
    if (c < 256) { int r = c >> 5, h = c & 31; v = ldf(W1, (r * IN_DIM + f) * HID + h, flags[1]); }
    else         { v = ldf(root1, f * HID + (c - 256), flags[2]); }
    w1t[c * IN_DIM + f] = f2bf(v);
}
__global__ __launch_bounds__(256) void prep_w2c(const void* __restrict__ W2,
                                                const void* __restrict__ root2,
                                                short* __restrict__ w2ct,
                                                const int* __restrict__ flags) {
    int i = blockIdx.x * 256 + threadIdx.x;
    if (i >= ODIM * L2K) return;
    int c = i / L2K, k = i % L2K;
    float v;
    if (k < 256) { int r = k >> 5, kk = k & 31; v = ldf(W2, (r * HID + kk) * ODIM + c, flags[3]); }
    else         { v = ldf(root2, (k - 256) * ODIM + c, flags[4]); }
    w2ct[c * L2K + k] = f2bf(v);
}
__global__ __launch_bounds__(256) void prep_small(const short* __restrict__ b1,
                                                  const short* __restrict__ b2,
                                                  const void* __restrict__ lin_w,
                                                  const short* __restrict__ lin_b,
                                                  short* __restrict__ smallc,
                                                  const int* __restrict__ flags) {
    int i = threadIdx.x;
    if (i < 32)        smallc[i] = b1[i];
    else if (i < 96)   smallc[i] = b2[i - 32];
    else if (i < 224)  smallc[i] = f2bf(ldf(lin_w, i - 96, flags[5]));
    else if (i < 226)  smallc[i] = lin_b[i - 224];
}

// ---- CSR pass 1: WG-private coarse-bucket scatter ----
// record = (dst&127)<<20 | src<<3 | rel
__global__ __launch_bounds__(1024) void scatter_coarse(const int* __restrict__ ei,
                                                       const int* __restrict__ et,
                                                       int* __restrict__ cnt,
                                                       int* __restrict__ seg, int E,
                                                       const int* __restrict__ flags) {
    __shared__ int cur[NCB];
    if (threadIdx.x < NCB) cur[threadIdx.x] = 0;
    __syncthreads();
    int i64 = flags[6], t64 = flags[7];
    int epw = (E + NWGS - 1) / NWGS;
    int lo = blockIdx.x * epw;
    int hi = lo + epw; if (hi > E) hi = E;
    for (int i = lo + threadIdx.x; i < hi; i += 1024) {
        int s = ldi(ei, i, i64);
        int d = ldi(ei, (long long)E + i, i64);
        int r = ldi(et, i, t64);
        int cb = d >> 7;
        int pos = atomicAdd(&cur[cb], 1);
        if (pos < CCAP)
            seg[(cb * NWGS + (int)blockIdx.x) * CCAP + pos] = ((d & 127) << 20) | (s << 3) | r;
    }
    __syncthreads();
    if (threadIdx.x < NCB) {
        int c = cur[threadIdx.x];
        cnt[blockIdx.x * NCB + threadIdx.x] = c < CCAP ? c : CCAP;
    }
}

// ---- CSR pass 2a: per-cb totals in parallel (784 WGs, wave reduce) ----
__global__ __launch_bounds__(64) void cb_sum(const int* __restrict__ cnt,
                                             int* __restrict__ cbTot) {
    int cb = blockIdx.x, lane = threadIdx.x;
    int t = 0;
    for (int g = lane; g < NWGS; g += 64) t += cnt[g * NCB + cb];
#pragma unroll
    for (int o = 32; o > 0; o >>= 1) t += __shfl_down(t, o, 64);
    if (lane == 0) cbTot[cb] = t;
}

// ---- CSR pass 2b: scan 784 totals -> cbBase; off[NN] = E ----
__global__ __launch_bounds__(1024) void cb_scan2(const int* __restrict__ cbTot,
                                                 int* __restrict__ cbBase,
                                                 int* __restrict__ off) {
    __shared__ int s[1024];
    int t = threadIdx.x;
    int v = (t < NCB) ? cbTot[t] : 0;
    s[t] = v; __syncthreads();
    for (int o = 1; o < 1024; o <<= 1) {
        int u = (t >= o) ? s[t - o] : 0;
        __syncthreads();
        s[t] += u;
        __syncthreads();
    }
    if (t < NCB) cbBase[t] = s[t] - v;
    if (t == NCB - 1) off[NN] = s[t];
}

// ---- CSR pass 3: per-cb (128 nodes) LDS sort -> off/inv_deg + packed ----
__global__ __launch_bounds__(256) void build_cb(const int* __restrict__ cnt,
                                                const int* __restrict__ seg,
                                                const int* __restrict__ cbBase,
                                                int* __restrict__ off,
                                                float* __restrict__ inv_deg,
                                                int* __restrict__ packed) {
    __shared__ int cntl[NWGS], soff[NWGS];
    __shared__ int recs[RECCAP];
    __shared__ int degl[128], basel[128], kcur[128];
    __shared__ int stmp[256];
    int cb = blockIdx.x, tid = threadIdx.x;
    if (tid < NWGS) cntl[tid] = cnt[tid * NCB + cb];
    if (tid < 128) degl[tid] = 0;
    __syncthreads();
    int v = (tid < NWGS) ? cntl[tid] : 0;
    stmp[tid] = v; __syncthreads();
    for (int o = 1; o < 256; o <<= 1) {
        int u = (tid >= o) ? stmp[tid - o] : 0;
        __syncthreads();
        stmp[tid] += u;
        __syncthreads();
    }
    if (tid < NWGS) soff[tid] = stmp[tid] - v;
    int tot = stmp[255]; if (tot > RECCAP) tot = RECCAP;
    __syncthreads();
    int wave = tid >> 6, lane = tid & 63;
    for (int g = wave; g < NWGS; g += 4) {
        int c = cntl[g], b = soff[g];
        const int* sp = seg + (cb * NWGS + g) * CCAP;
        for (int e = lane; e < c; e += 64)
            if (b + e < RECCAP) recs[b + e] = sp[e];
    }
    __syncthreads();
    for (int i = tid; i < tot; i += 256) atomicAdd(&degl[recs[i] >> 20], 1);
    __syncthreads();
    int dv = (tid < 128) ? degl[tid] : 0;
    stmp[tid] = dv; __syncthreads();
    for (int o = 1; o < 128; o <<= 1) {
        int u = (tid >= o) ? stmp[tid - o] : 0;
        __syncthreads();
        stmp[tid] += u;
        __syncthreads();
    }
    int gbase = cbBase[cb];
    if (tid < 128) {
        int excl = stmp[tid] - dv;
        basel[tid] = excl;
        kcur[tid] = 0;
        int node = cb * 128 + tid;
        if (node < NN) {
            off[node] = gbase + excl;
            inv_deg[node] = 1.0f / (float)(dv > 1 ? dv : 1);
        }
    }
    __syncthreads();
    for (int i = tid; i < tot; i += 256) {
        int rec = recs[i];
        int n = rec >> 20;
        int p = atomicAdd(&kcur[n], 1);
        packed[gbase + basel[n] + p] = rec & 0xFFFFF;   // src<<3 | rel
    }
}

// ---- GEMM1: [N,128] x w1t[288,128]^T -> xw [N,288] bf16; 64 rows/wave
__global__ __launch_bounds__(256) void gemm1(const void* __restrict__ x,
                                             const short* __restrict__ w1t,
                                             short* __restrict__ xw,
                                             const int* __restrict__ flags) {
    int wave = threadIdx.x >> 6, lane = threadIdx.x & 63;
    int m = lane & 15, quad = lane >> 4;
    int row0 = (blockIdx.x * 4 + wave) * 64;
    if (row0 >= NN) return;

    bf16x8 a[4][4];
    int fp32 = flags[0];
#pragma unroll
    for (int t = 0; t < 4; ++t) {
        int row = row0 + t * 16 + m;
        int rc = row < NN ? row : NN - 1;
        if (fp32) {
            const float* xr = (const float*)x + rc * IN_DIM + quad * 8;
#pragma unroll
            for (int kt = 0; kt < 4; ++kt) {
                const f32x4* q = (const f32x4*)(xr + kt * 32);
                f32x4 u0 = q[0], u1 = q[1];
                bf16x8 tt;
                tt[0] = f2bf(u0[0]); tt[1] = f2bf(u0[1]); tt[2] = f2bf(u0[2]); tt[3] = f2bf(u0[3]);
                tt[4] = f2bf(u1[0]); tt[5] = f2bf(u1[1]); tt[6] = f2bf(u1[2]); tt[7] = f2bf(u1[3]);
                a[t][kt] = tt;
            }
        } else {
            const short* xr = (const short*)x + rc * IN_DIM + quad * 8;
#pragma unroll
            for (int kt = 0; kt < 4; ++kt) a[t][kt] = *(const bf16x8*)(xr + kt * 32);
        }
    }

    for (int ct = 0; ct < 18; ++ct) {
        const short* wp = w1t + (ct * 16 + m) * IN_DIM + quad * 8;
        bf16x8 b[4];
#pragma unroll
        for (int kt = 0; kt < 4; ++kt) b[kt] = *(const bf16x8*)(wp + kt * 32);
#pragma unroll
        for (int t = 0; t < 4; ++t) {
            f32x4 acc = {0.f, 0.f, 0.f, 0.f};
#pragma unroll
            for (int kt = 0; kt < 4; ++kt)
                acc = __builtin_amdgcn_mfma_f32_16x16x32_bf16(a[t][kt], b[kt], acc, 0, 0, 0);
#pragma unroll
            for (int i = 0; i < 4; ++i) {
                int r = row0 + t * 16 + quad * 4 + i;
                if (r < NN) xw[r * L1C + ct * 16 + m] = f2bf(acc[i]);
            }
        }
    }
}

// ---- layer-1 aggregation: 32 lanes/node, unroll-4 gathers -> h (ReLU'd)
__global__ __launch_bounds__(256) void agg1(const short* __restrict__ xw,
                                            const int* __restrict__ off,
                                            const int* __restrict__ packed,
                                            const float* __restrict__ inv_deg,
                                            const short* __restrict__ smallc,
                                            short* __restrict__ h) {
    int lane = threadIdx.x & 31;
    int node = blockIdx.x * 8 + (threadIdx.x >> 5);
    if (node >= NN) return;
    int s = off[node], e = off[node + 1];
    float acc = 0.f;
    int i = s;
    for (; i + 3 < e; i += 4) {
        int pk0 = packed[i], pk1 = packed[i + 1], pk2 = packed[i + 2], pk3 = packed[i + 3];
        float v0 = bf2f(xw[(pk0 >> 3) * L1C + (pk0 & 7) * 32 + lane]);
        float v1 = bf2f(xw[(pk1 >> 3) * L1C + (pk1 & 7) * 32 + lane]);
        float v2 = bf2f(xw[(pk2 >> 3) * L1C + (pk2 & 7) * 32 + lane]);
        float v3 = bf2f(xw[(pk3 >> 3) * L1C + (pk3 & 7) * 32 + lane]);
        acc += (v0 + v1) + (v2 + v3);
    }
    for (; i < e; ++i) {
        int pk = packed[i];
        acc += bf2f(xw[(pk >> 3) * L1C + (pk & 7) * 32 + lane]);
    }
    float v = acc * inv_deg[node] + bf2f(xw[node * L1C + 256 + lane]) + bf2f(smallc[lane]);
    h[node * HID + lane] = f2bf(v > 0.f ? v : 0.f);
}

// ---- fused layer-2: predicated aggregate (regs) -> LDS -> MFMA -> classify
__global__ __launch_bounds__(256) void agg2_fused(const short* __restrict__ h,
                                                  const int* __restrict__ off,
                                                  const int* __restrict__ packed,
                                                  const float* __restrict__ inv_deg,
                                                  const short* __restrict__ w2ct,
                                                  const short* __restrict__ smallc,
                                                  float* __restrict__ out) {
    __shared__ __align__(16) short g2l[16 * G2ST];
    __shared__ float red[4][16][2];
    int tid = threadIdx.x;
    int lane31 = tid & 31, gi = tid >> 5;
    int row0 = blockIdx.x * 16;

    // phase A: each 32-lane group aggregates 2 nodes (8 predicated accumulators)
    for (int s2 = 0; s2 < 2; ++s2) {
        int n = row0 + gi * 2 + s2;
        int st = off[n], e = off[n + 1];
        float a0 = 0, a1 = 0, a2 = 0, a3 = 0, a4 = 0, a5 = 0, a6 = 0, a7 = 0;
        int i = st;
        for (; i + 3 < e; i += 4) {
            int pk0 = packed[i], pk1 = packed[i + 1], pk2 = packed[i + 2], pk3 = packed[i + 3];
            float v0 = bf2f(h[(pk0 >> 3) * HID + lane31]);
            float v1 = bf2f(h[(pk1 >> 3) * HID + lane31]);
            float v2 = bf2f(h[(pk2 >> 3) * HID + lane31]);
            float v3 = bf2f(h[(pk3 >> 3) * HID + lane31]);
            int r0 = pk0 & 7, r1 = pk1 & 7, r2 = pk2 & 7, r3 = pk3 & 7;
            a0 += ((r0 == 0) ? v0 : 0.f) + ((r1 == 0) ? v1 : 0.f) + ((r2 == 0) ? v2 : 0.f) + ((r3 == 0) ? v3 : 0.f);
            a1 += ((r0 == 1) ? v0 : 0.f) + ((r1 == 1) ? v1 : 0.f) + ((r2 == 1) ? v2 : 0.f) + ((r3 == 1) ? v3 : 0.f);
            a2 += ((r0 == 2) ? v0 : 0.f) + ((r1 == 2) ? v1 : 0.f) + ((r2 == 2) ? v2 : 0.f) + ((r3 == 2) ? v3 : 0.f);
            a3 += ((r0 == 3) ? v0 : 0.f) + ((r1 == 3) ? v1 : 0.f) + ((r2 == 3) ? v2 : 0.f) + ((r3 == 3) ? v3 : 0.f);
            a4 += ((r0 == 4) ? v0 : 0.f) + ((r1 == 4) ? v1 : 0.f) + ((r2 == 4) ? v2 : 0.f) + ((r3 == 4) ? v3 : 0.f);
            a5 += ((r0 == 5) ? v0 : 0.f) + ((r1 == 5) ? v1 : 0.f) + ((r2 == 5) ? v2 : 0.f) + ((r3 == 5) ? v3 : 0.f);
            a6 += ((r0 == 6) ? v0 : 0.f) + ((r1 == 6) ? v1 : 0.f) + ((r2 == 6) ? v2 : 0.f) + ((r3 == 6) ? v3 : 0.f);
            a7 += ((r0 == 7) ? v0 : 0.f) + ((r1 == 7) ? v1 : 0.f) + ((r2 == 7) ? v2 : 0.f) + ((r3 == 7) ? v3 : 0.f);
        }
        for (; i < e; ++i) {
            int pk = packed[i];
            float v = bf2f(h[(pk >> 3) * HID + lane31]);
            int r = pk & 7;
            a0 += (r == 0) ? v : 0.f;  a1 += (r == 1) ? v : 0.f;
            a2 += (r == 2) ? v : 0.f;  a3 += (r == 3) ? v : 0.f;
            a4 += (r == 4) ? v : 0.f;  a5 += (r == 5) ? v : 0.f;
            a6 += (r == 6) ? v : 0.f;  a7 += (r == 7) ? v : 0.f;
        }
        float sc = inv_deg[n];
        int base = (gi * 2 + s2) * G2ST;
        g2l[base +   0 + lane31] = f2bf(a0 * sc);
        g2l[base +  32 + lane31] = f2bf(a1 * sc);
        g2l[base +  64 + lane31] = f2bf(a2 * sc);
        g2l[base +  96 + lane31] = f2bf(a3 * sc);
        g2l[base + 128 + lane31] = f2bf(a4 * sc);
        g2l[base + 160 + lane31] = f2bf(a5 * sc);
        g2l[base + 192 + lane31] = f2bf(a6 * sc);
        g2l[base + 224 + lane31] = f2bf(a7 * sc);
        g2l[base + 256 + lane31] = h[n * HID + lane31];
    }
    __syncthreads();

    // phase B: 4 waves, wave = 16-col block; MFMA over K=288 from LDS
    int wave = tid >> 6, lane = tid & 63;
    int m = lane & 15, quad = lane >> 4;
    const short* wp = w2ct + (wave * 16 + m) * L2K + quad * 8;
    bf16x8 a[9], b[9];
#pragma unroll
    for (int kt = 0; kt < 9; ++kt) {
        b[kt] = *(const bf16x8*)(wp + kt * 32);
        a[kt] = *(const bf16x8*)(&g2l[m * G2ST + quad * 8 + kt * 32]);
    }
    f32x4 acc = {0.f, 0.f, 0.f, 0.f};
#pragma unroll
    for (int kt = 0; kt < 9; ++kt)
        acc = __builtin_amdgcn_mfma_f32_16x16x32_bf16(a[kt], b[kt], acc, 0, 0, 0);

    int c = wave * 16 + m;
    float lw0 = bf2f(smallc[96 + c * 2 + 0]);
    float lw1 = bf2f(smallc[96 + c * 2 + 1]);
    float b2c = bf2f(smallc[32 + c]);
    float pr0[4], pr1[4];
#pragma unroll
    for (int i = 0; i < 4; ++i) {
        float v = acc[i] + b2c;
        pr0[i] = v * lw0;
        pr1[i] = v * lw1;
    }
#pragma unroll
    for (int o = 1; o < 16; o <<= 1) {
#pragma unroll
        for (int i = 0; i < 4; ++i) {
            pr0[i] += __shfl_xor(pr0[i], o, 64);
            pr1[i] += __shfl_xor(pr1[i], o, 64);
        }
    }
    if (m == 0) {
#pragma unroll
        for (int i = 0; i < 4; ++i) {
            red[wave][quad * 4 + i][0] = pr0[i];
            red[wave][quad * 4 + i][1] = pr1[i];
        }
    }
    __syncthreads();
    if (tid < 32) {
        int row = tid >> 1, j = tid & 1;
        float v = red[0][row][j] + red[1][row][j] + red[2][row][j] + red[3][row][j]
                + bf2f(smallc[224 + j]);
        out[(row0 + row) * 2 + j] = v;
    }
}

extern "C" void kernel_launch(void* const* d_in, const int* in_sizes, int n_in,
                              void* d_out, int out_size, void* d_ws, size_t ws_size,
                              hipStream_t stream) {
    const void* x     = d_in[0];
    const int*  ei    = (const int*)d_in[1];
    const int*  etype = (const int*)d_in[2];
    const void* W1    = d_in[3];
    const void* root1 = d_in[4];
    const void* b1    = d_in[5];
    const void* W2    = d_in[6];
    const void* root2 = d_in[7];
    const void* b2    = d_in[8];
    const void* lin_w = d_in[9];
    const void* lin_b = d_in[10];
    float* out = (float*)d_out;          // fp32 output (verified round 4)

    const int E = in_sizes[2];          // 1,600,000

    // workspace carve (256B aligned). Peak ~100 MB.
    char* p = (char*)d_ws;
    auto alloc = [&](size_t bytes) { char* r = p; p += (bytes + 255) & ~(size_t)255; return (void*)r; };
    int*   flags   = (int*)  alloc(256);
    int*   off     = (int*)  alloc((size_t)(NN + 1) * 4);
    float* inv_deg = (float*)alloc((size_t)NN * 4);
    int*   packed  = (int*)  alloc((size_t)E * 4);
    int*   cnt     = (int*)  alloc((size_t)NWGS * NCB * 4);
    int*   cbTot   = (int*)  alloc((size_t)NCB * 4);
    int*   cbBase  = (int*)  alloc((size_t)NCB * 4);
    int*   seg     = (int*)  alloc((size_t)NCB * NWGS * CCAP * 4);   // 24.6 MB
    short* w1t     = (short*)alloc((size_t)L1C * IN_DIM * 2);
    short* w2ct    = (short*)alloc((size_t)ODIM * L2K * 2);
    short* smallc  = (short*)alloc(256 * 2);
    short* h       = (short*)alloc((size_t)NN * HID * 2);
    short* xw1     = (short*)alloc((size_t)NN * L1C * 2);            // 57.6 MB

    detect<<<1, 256, 0, stream>>>((const short*)x, (const short*)W1, (const short*)root1,
                                  (const short*)W2, (const short*)root2, (const short*)lin_w,
                                  ei, etype, flags);
    prep_w1<<<(L1C * IN_DIM + 255) / 256, 256, 0, stream>>>(W1, root1, w1t, flags);
    prep_w2c<<<(ODIM * L2K + 255) / 256, 256, 0, stream>>>(W2, root2, w2ct, flags);
    prep_small<<<1, 256, 0, stream>>>((const short*)b1, (const short*)b2, lin_w,
                                      (const short*)lin_b, smallc, flags);

    scatter_coarse<<<NWGS, 1024, 0, stream>>>(ei, etype, cnt, seg, E, flags);
    cb_sum<<<NCB, 64, 0, stream>>>(cnt, cbTot);
    cb_scan2<<<1, 1024, 0, stream>>>(cbTot, cbBase, off);
    build_cb<<<NCB, 256, 0, stream>>>(cnt, seg, cbBase, off, inv_deg, packed);

    gemm1<<<((NN + 63) / 64 + 3) / 4, 256, 0, stream>>>(x, w1t, xw1, flags);
    agg1<<<(NN + 7) / 8, 256, 0, stream>>>(xw1, off, packed, inv_deg, smallc, h);
    agg2_fused<<<NN / 16, 256, 0, stream>>>(h, off, packed, inv_deg, w2ct, smallc, out);
}